// Round 1
// 236.128 us; speedup vs baseline: 1.1194x; 1.1194x over previous
//
#include <hip/hip_runtime.h>
#include <hip/hip_bf16.h>
#include <float.h>
#include <math.h>

// B=4, S=4096, D=2048, E=64, K=2
#define B_DIM 4
#define S_DIM 4096
#define D_DIM 2048
#define E_DIM 64
#define N_TOK 16384
#define TOKS 32              // tokens per block
#define NBLK (N_TOK / TOKS)  // 512 blocks (2/CU)
#define NTHR 512             // 8 waves: (token-half g) x (D-slice sl)
#define BK 64                // K-tile per step
#define LDK 72               // padded LDS row (ushort): 144 B, 2-way banks (free)
#define SLICES 4             // split-K factor
#define DSLICE (D_DIM / SLICES)  // 512
#define KSTEPS (DSLICE / BK)     // 8
#define GAP_THRESH 1e-3f
#define MAXFLAG 16

typedef __bf16 bf16x8_t __attribute__((ext_vector_type(8)));
typedef float f32x4_t __attribute__((ext_vector_type(4)));

union U8 { bf16x8_t v; unsigned short u[8]; };

// truncating fp32 -> (bf16 hi, bf16 lo) split; hi+lo captures ~16 mantissa bits
__device__ __forceinline__ void split2(float f, unsigned short& h, unsigned short& l) {
    unsigned int u = __float_as_uint(f);
    h = (unsigned short)(u >> 16);
    float hf = __uint_as_float(u & 0xFFFF0000u);
    l = (unsigned short)(__float_as_uint(f - hf) >> 16);  // exact residual (Sterbenz)
}

__global__ __launch_bounds__(NTHR, 4) void router_main(
    const float* __restrict__ x, const float* __restrict__ W,
    const float* __restrict__ gamma, const float* __restrict__ beta,
    const float* __restrict__ temperature,
    float* __restrict__ out_rw, float* __restrict__ out_dp,
    float* __restrict__ g_zsum, float* __restrict__ g_load)
{
    // 72 KB arena: W hi/lo planes during GEMM; partials + logits afterwards
    __shared__ __align__(16) unsigned char shraw[SLICES * 64 * LDK * 2 * 2]; // 73728 B
    typedef unsigned short WPlane[64][LDK];
    WPlane* const wh = (WPlane*)shraw;                                        // [SLICES][64][LDK]
    WPlane* const wl = (WPlane*)(shraw + SLICES * 64 * LDK * sizeof(unsigned short));
    typedef float PartT[TOKS][E_DIM + 2];
    PartT* const part = (PartT*)shraw;                                        // [SLICES][32][66]
    float (* const lgt)[E_DIM + 1] =
        (float (*)[E_DIM + 1])(shraw + SLICES * TOKS * (E_DIM + 2) * sizeof(float)); // [32][65]

    __shared__ float lgm[E_DIM], lbt[E_DIM], loadsum[E_DIM];
    __shared__ float smu[TOKS], srs[TOKS], sinv[TOKS];
    __shared__ int sel1[TOKS], sel2[TOKS];
    __shared__ int ftok[MAXFLAG], fcand[MAXFLAG][3];
    __shared__ int nflag;

    const int tid = threadIdx.x;
    const int tokBase = blockIdx.x * TOKS;
    const int lane = tid & 63;
    const int wv = tid >> 6;       // 0..7
    const int g  = wv & 1;         // token half: tokens g*16 .. g*16+15
    const int sl = wv >> 1;        // D-slice 0..3
    const int l15 = lane & 15;
    const int quad = lane >> 4;

    if (tid == 0) nflag = 0;
    if (tid < E_DIM) { lgm[tid] = gamma[tid]; lbt[tid] = beta[tid]; loadsum[tid] = 0.f; }

    // W staging: 128 threads per slice; 2 threads/row, 32 floats each (8 float4)
    const int sslice = tid >> 7;           // 0..3
    const int rowW = (tid & 127) >> 1;     // 0..63
    const int colW = (tid & 1) * 32;
    const float* wp = W + (size_t)rowW * D_DIM + sslice * DSLICE + colW;

    // x direct per-lane A-fragment base: row = token, col = slice base + quad*8
    const float* xp = x + (size_t)(tokBase + g * 16 + l15) * D_DIM + sl * DSLICE + quad * 8;

    f32x4_t acc[4];
    #pragma unroll
    for (int t = 0; t < 4; ++t) acc[t] = (f32x4_t){0.f, 0.f, 0.f, 0.f};

    float4 wreg[8], xq[4], xn[4];
    // prologue: load+stage W(0), load x(0)
    #pragma unroll
    for (int j = 0; j < 8; ++j) wreg[j] = *(const float4*)(wp + j * 4);
    #pragma unroll
    for (int c = 0; c < 2; ++c) {
        xq[c * 2]     = *(const float4*)(xp + c * 32);
        xq[c * 2 + 1] = *(const float4*)(xp + c * 32 + 4);
    }
    #pragma unroll
    for (int j = 0; j < 8; ++j) {
        ushort4 h, l;
        split2(wreg[j].x, h.x, l.x); split2(wreg[j].y, h.y, l.y);
        split2(wreg[j].z, h.z, l.z); split2(wreg[j].w, h.w, l.w);
        *(ushort4*)&wh[sslice][rowW][colW + j * 4] = h;
        *(ushort4*)&wl[sslice][rowW][colW + j * 4] = l;
    }
    __syncthreads();

    for (int s = 0; s < KSTEPS; ++s) {
        const bool more = (s + 1 < KSTEPS);
        if (more) {  // prefetch next step's W (regs) and x (regs)
            const float* wq = wp + (s + 1) * BK;
            #pragma unroll
            for (int j = 0; j < 8; ++j) wreg[j] = *(const float4*)(wq + j * 4);
            const float* xg = xp + (s + 1) * BK;
            #pragma unroll
            for (int c = 0; c < 2; ++c) {
                xn[c * 2]     = *(const float4*)(xg + c * 32);
                xn[c * 2 + 1] = *(const float4*)(xg + c * 32 + 4);
            }
        }
        #pragma unroll
        for (int h = 0; h < 2; ++h) {
            float tf[8] = {xq[h*2].x, xq[h*2].y, xq[h*2].z, xq[h*2].w,
                           xq[h*2+1].x, xq[h*2+1].y, xq[h*2+1].z, xq[h*2+1].w};
            U8 ah, al;
            #pragma unroll
            for (int k = 0; k < 8; ++k) split2(tf[k], ah.u[k], al.u[k]);
            #pragma unroll
            for (int t = 0; t < 4; ++t) {
                U8 bh, bl;
                bh.v = *(const bf16x8_t*)&wh[sl][t * 16 + l15][h * 32 + quad * 8];
                bl.v = *(const bf16x8_t*)&wl[sl][t * 16 + l15][h * 32 + quad * 8];
                acc[t] = __builtin_amdgcn_mfma_f32_16x16x32_bf16(ah.v, bh.v, acc[t], 0, 0, 0);
                acc[t] = __builtin_amdgcn_mfma_f32_16x16x32_bf16(ah.v, bl.v, acc[t], 0, 0, 0);
                acc[t] = __builtin_amdgcn_mfma_f32_16x16x32_bf16(al.v, bh.v, acc[t], 0, 0, 0);
            }
        }
        __syncthreads();           // all LDS reads of this step done
        if (more) {                // single-buffered: overwrite with next tile
            #pragma unroll
            for (int j = 0; j < 8; ++j) {
                ushort4 h, l;
                split2(wreg[j].x, h.x, l.x); split2(wreg[j].y, h.y, l.y);
                split2(wreg[j].z, h.z, l.z); split2(wreg[j].w, h.w, l.w);
                *(ushort4*)&wh[sslice][rowW][colW + j * 4] = h;
                *(ushort4*)&wl[sslice][rowW][colW + j * 4] = l;
            }
            #pragma unroll
            for (int j = 0; j < 4; ++j) xq[j] = xn[j];
            __syncthreads();       // next tile visible
        }
    }

    // phase A: partial acc -> LDS (W arena dead after final post-MFMA barrier)
    // C/D: col(n)=lane&15, row(m)=quad*4+reg
    #pragma unroll
    for (int t = 0; t < 4; ++t)
        #pragma unroll
        for (int r = 0; r < 4; ++r)
            part[sl][g * 16 + quad * 4 + r][t * 16 + l15] = acc[t][r];
    __syncthreads();

    // split-K reduction: 4 partials -> logits (fixed pairwise order, deterministic)
    for (int i = tid; i < TOKS * E_DIM; i += NTHR) {
        int r = i >> 6, c = i & 63;
        lgt[r][c] = (part[0][r][c] + part[1][r][c]) + (part[2][r][c] + part[3][r][c]);
    }
    __syncthreads();

    // phase B: waves 0-1 only; 4 lanes per token (quad = expert quarter)
    if (wv < 2) {
        const int tok = wv * 16 + l15;
        const int q = quad;
        const float it = 1.f / (temperature[0] + 1e-6f);
        float s1 = 0.f, s2 = 0.f;
        #pragma unroll
        for (int e = 0; e < 16; ++e) { float v = lgt[tok][q * 16 + e]; s1 += v; s2 += v * v; }
        s1 += __shfl_xor(s1, 16); s1 += __shfl_xor(s1, 32);
        s2 += __shfl_xor(s2, 16); s2 += __shfl_xor(s2, 32);
        const float mu  = s1 * (1.f / 64.f);
        const float var = s2 * (1.f / 64.f) - mu * mu;   // biased, matches ref
        const float rs  = rsqrtf(var + 1e-5f);
        if (q == 0) { smu[tok] = mu; srs[tok] = rs; }

        float m0 = -FLT_MAX, m1 = -FLT_MAX, m2 = -FLT_MAX;
        int   i0 = -1, i1 = -1, i2 = -1;
        float zl = 0.f;
        #pragma unroll
        for (int e = 0; e < 16; ++e) {
            int c = q * 16 + e;
            float y = (lgt[tok][c] - mu) * rs * lgm[c] + lbt[c];
            lgt[tok][c] = y;
            zl += y * y;
            if (y > m0)      { m2 = m1; i2 = i1; m1 = m0; i1 = i0; m0 = y; i0 = c; }
            else if (y > m1) { m2 = m1; i2 = i1; m1 = y; i1 = c; }
            else if (y > m2) { m2 = y; i2 = c; }
        }
        // merge sorted top-3 triples across quad lanes (3+3 merge, low-index tie-break)
        #pragma unroll
        for (int d = 16; d <= 32; d <<= 1) {
            float n0 = __shfl_xor(m0, d), n1 = __shfl_xor(m1, d), n2 = __shfl_xor(m2, d);
            int   j0 = __shfl_xor(i0, d), j1 = __shfl_xor(i1, d), j2 = __shfl_xor(i2, d);
            bool t0 = (m0 > n0) || (m0 == n0 && i0 < j0);
            float r0v = t0 ? m0 : n0; int r0i = t0 ? i0 : j0;
            float A0v = t0 ? m1 : m0; int A0i = t0 ? i1 : i0;
            float A1v = t0 ? m2 : m1; int A1i = t0 ? i2 : i1;
            float B0v = t0 ? n0 : n1; int B0i = t0 ? j0 : j1;
            float B1v = t0 ? n1 : n2; int B1i = t0 ? j1 : j2;
            bool t1 = (A0v > B0v) || (A0v == B0v && A0i < B0i);
            float r1v = t1 ? A0v : B0v; int r1i = t1 ? A0i : B0i;
            float A0w = t1 ? A1v : A0v; int A0j = t1 ? A1i : A0i;
            float B0w = t1 ? B0v : B1v; int B0j = t1 ? B0i : B1i;
            bool t2 = (A0w > B0w) || (A0w == B0w && A0j < B0j);
            float r2v = t2 ? A0w : B0w; int r2i = t2 ? A0j : B0j;
            m0 = r0v; i0 = r0i; m1 = r1v; i1 = r1i; m2 = r2v; i2 = r2i;
        }
        if (q == 0) {
            sel1[tok] = i0; sel2[tok] = i1;
            if (m1 - m2 < GAP_THRESH) {   // rank2/rank3 near-tie -> fp64 fix-up
                int sf = atomicAdd(&nflag, 1);
                if (sf < MAXFLAG) { ftok[sf] = tok; fcand[sf][0] = i0; fcand[sf][1] = i1; fcand[sf][2] = i2; }
            }
        }
        // softmax (store unnormalized exp; scale at write time)
        float es = 0.f;
        #pragma unroll
        for (int e = 0; e < 16; ++e) {
            int c = q * 16 + e;
            float ev = __expf((lgt[tok][c] - m0) * it);
            lgt[tok][c] = ev; es += ev;
        }
        es += __shfl_xor(es, 16); es += __shfl_xor(es, 32);
        if (q == 0) sinv[tok] = 1.f / es;
        // z-loss: full-wave reduce (covers this wave's 16 tokens x 64 experts)
        zl += __shfl_xor(zl, 1); zl += __shfl_xor(zl, 2); zl += __shfl_xor(zl, 4);
        zl += __shfl_xor(zl, 8); zl += __shfl_xor(zl, 16); zl += __shfl_xor(zl, 32);
        if (lane == 0) atomicAdd(g_zsum, zl);
    }
    __syncthreads();

    // phase C: cooperative fp64 re-rank of flagged tokens' top-3 candidates (8 waves)
    const int nf = min(nflag, MAXFLAG);
    for (int f = wv; f < nf; f += 8) {
        const int tk = ftok[f];
        const int c0 = fcand[f][0], c1 = fcand[f][1], c2 = fcand[f][2];
        const float* xr = x + (size_t)(tokBase + tk) * D_DIM;
        const float* w0 = W + (size_t)c0 * D_DIM;
        const float* w1 = W + (size_t)c1 * D_DIM;
        const float* w2 = W + (size_t)c2 * D_DIM;
        double L0 = 0.0, L1 = 0.0, L2 = 0.0;
        for (int i = lane; i < D_DIM; i += 64) {
            double xv = (double)xr[i];
            L0 += xv * (double)w0[i];
            L1 += xv * (double)w1[i];
            L2 += xv * (double)w2[i];
        }
        #pragma unroll
        for (int off = 32; off; off >>= 1) {
            L0 += __shfl_down(L0, off);
            L1 += __shfl_down(L1, off);
            L2 += __shfl_down(L2, off);
        }
        if (lane == 0) {
            double dmu = (double)smu[tk], drs = (double)srs[tk];
            double y0 = (L0 - dmu) * drs * (double)lgm[c0] + (double)lbt[c0];
            double y1 = (L1 - dmu) * drs * (double)lgm[c1] + (double)lbt[c1];
            double y2 = (L2 - dmu) * drs * (double)lgm[c2] + (double)lbt[c2];
            bool g01 = (y0 > y1) || (y0 == y1 && c0 < c1);
            bool g02 = (y0 > y2) || (y0 == y2 && c0 < c2);
            bool g12 = (y1 > y2) || (y1 == y2 && c1 < c2);
            int a, b;
            if (!g01 && !g02)      { a = c1; b = c2; }   // elem0 loses both
            else if (g01 && !g12)  { a = c0; b = c2; }   // elem1 loses both
            else                   { a = c0; b = c1; }   // elem2 loses both
            sel1[tk] = a; sel2[tk] = b;
        }
    }
    __syncthreads();

    // phase D: expert-load accumulation (selection-dependent, post-fix-up)
    if (tid < TOKS) {
        float inv = sinv[tid];
        atomicAdd(&loadsum[sel1[tid]], lgt[tid][sel1[tid]] * inv);
        atomicAdd(&loadsum[sel2[tid]], lgt[tid][sel2[tid]] * inv);
    }
    __syncthreads();
    if (tid < E_DIM) atomicAdd(&g_load[(tokBase >> 12) * E_DIM + tid], loadsum[tid]);

    // phase E: coalesced outputs (8 KB per array per block)
    float* orw = out_rw + (size_t)tokBase * E_DIM;
    float* odp = out_dp + (size_t)tokBase * E_DIM;
    for (int i = tid; i < TOKS * E_DIM; i += NTHR) {
        int r = i >> 6, c = i & 63;
        float p = lgt[r][c] * sinv[r];
        orw[i] = p;
        odp[i] = (c == sel1[r] || c == sel2[r]) ? p : 0.f;
    }
}

__global__ void router_fin(const float* __restrict__ ws, float* __restrict__ out_loss) {
    __shared__ float sv[B_DIM * E_DIM];
    const int tid = threadIdx.x;
    sv[tid] = ws[8 + tid] * (1.f / S_DIM);   // expert_load[b][e]
    __syncthreads();
    if (tid == 0) {
        float s = 0.f;
        for (int i = 0; i < B_DIM * E_DIM; ++i) s += sv[i];
        const float mean = s * (1.f / (B_DIM * E_DIM));
        float ss = 0.f;
        for (int i = 0; i < B_DIM * E_DIM; ++i) { float d = sv[i] - mean; ss += d * d; }
        const float sd = sqrtf(ss * (1.f / (B_DIM * E_DIM - 1)));  // ddof=1
        const float z = ws[0] * (1.f / ((float)N_TOK * E_DIM));
        out_loss[0] = 0.001f * z + 0.1f * (sd / mean) * 10.f;
    }
}

extern "C" void kernel_launch(void* const* d_in, const int* in_sizes, int n_in,
                              void* d_out, int out_size, void* d_ws, size_t ws_size,
                              hipStream_t stream) {
    const float* x     = (const float*)d_in[0];
    const float* W     = (const float*)d_in[1];
    const float* gamma = (const float*)d_in[2];
    const float* beta  = (const float*)d_in[3];
    const float* temp  = (const float*)d_in[4];
    float* out  = (float*)d_out;
    float* rw   = out;                                  // routing_weights [N, E]
    float* dp   = out + (size_t)N_TOK * E_DIM;          // dispatch [B, S, E]
    float* loss = out + 2 * (size_t)N_TOK * E_DIM;      // total_loss scalar
    float* ws   = (float*)d_ws;                         // [0]=zsum, [8..264)=load sums

    hipMemsetAsync(d_ws, 0, 512 * sizeof(float), stream);
    router_main<<<dim3(NBLK), dim3(NTHR), 0, stream>>>(x, W, gamma, beta, temp,
                                                       rw, dp, ws, ws + 8);
    router_fin<<<dim3(1), dim3(256), 0, stream>>>(ws, loss);
}